// Round 1
// baseline (1116.097 us; speedup 1.0000x reference)
//
#include <hip/hip_runtime.h>
#include <math.h>

#define HW 16384

using short8 = __attribute__((ext_vector_type(8))) short;
using f32x4  = __attribute__((ext_vector_type(4))) float;

__device__ __forceinline__ float bf2f(unsigned short u){
  union { unsigned int i; float f; } x; x.i = ((unsigned int)u) << 16; return x.f;
}
__device__ __forceinline__ unsigned short f2bf(float f){
  union { float f; unsigned int i; } x; x.f = f;
  return (unsigned short)((x.i + 0x7FFFu + ((x.i >> 16) & 1u)) >> 16);
}

// ---------------- weight fp32 -> bf16 ----------------
__global__ void castw_k(const float* __restrict__ in, unsigned short* __restrict__ out, int n){
  int i = blockIdx.x * 256 + threadIdx.x;
  if (i < n) out[i] = f2bf(in[i]);
}

// ---------------- time modulation: silu(t_emb) @ W^T + b ----------------
__global__ void modk(const float* __restrict__ t_emb,
                     const float* __restrict__ aw, const float* __restrict__ ab,
                     const float* __restrict__ fw, const float* __restrict__ fb,
                     float* __restrict__ mod_a, float* __restrict__ mod_f){
  int o = blockIdx.x * 128 + threadIdx.x;   // 0..383
  int b = blockIdx.y;
  const float* w  = blockIdx.z ? fw : aw;
  const float* bi = blockIdx.z ? fb : ab;
  float* outp     = blockIdx.z ? mod_f : mod_a;
  const float* te = t_emb + b * 256;
  float acc = bi[o];
  for (int k = 0; k < 256; ++k){
    float u = te[k];
    float s = u / (1.f + expf(-u));
    acc += s * w[o * 256 + k];
  }
  outp[b * 384 + o] = acc;
}

// ---------------- channel LayerNorm (ddof=1, std+eps) + modulate -> bf16 ----------------
// block = 256 = 64 pixels x 4 channel-groups(48ch). grid (256, B)
__global__ __launch_bounds__(256) void lnmod_k(const float* __restrict__ x,
                                               const float* __restrict__ nw, const float* __restrict__ nb,
                                               const float* __restrict__ mod, unsigned short* __restrict__ y){
  int b = blockIdx.y;
  int t = threadIdx.x;
  int pl = t & 63, cg = t >> 6;
  int p = blockIdx.x * 64 + pl;
  const float* xb = x + (size_t)b * 192 * HW + p;
  float s = 0.f, s2 = 0.f;
  #pragma unroll 8
  for (int c = cg * 48; c < cg * 48 + 48; ++c){
    float v = xb[(size_t)c * HW]; s += v; s2 += v * v;
  }
  __shared__ float rs[4][64], rq[4][64];
  rs[cg][pl] = s; rq[cg][pl] = s2;
  __syncthreads();
  float S  = rs[0][pl] + rs[1][pl] + rs[2][pl] + rs[3][pl];
  float S2 = rq[0][pl] + rq[1][pl] + rq[2][pl] + rq[3][pl];
  float mean = S * (1.f / 192.f);
  float var  = (S2 - S * mean) * (1.f / 191.f);
  float rinv = 1.f / (sqrtf(fmaxf(var, 0.f)) + 1e-6f);
  const float* mo = mod + b * 384;
  unsigned short* yb = y + (size_t)b * 192 * HW + p;
  #pragma unroll 8
  for (int c = cg * 48; c < cg * 48 + 48; ++c){
    float v = xb[(size_t)c * HW];
    float ln = nw[c] * ((v - mean) * rinv) + nb[c];
    yb[(size_t)c * HW] = f2bf(ln * (1.f + mo[c]) + mo[192 + c]);
  }
}

// ---------------- bf16 MFMA GEMM: out[b][m][n] = W[m][k] @ Act[b][k][n] + bias ----------------
#define BM 64
#define BN 128
#define BK 32
__global__ __launch_bounds__(256) void gemm_k(const unsigned short* __restrict__ A,
                                              const unsigned short* __restrict__ Bact,
                                              const float* __restrict__ bias,
                                              const float* resid, void* outp,
                                              int M, int K, int ofp32){
  const int N = HW;
  const unsigned short* Bp = Bact + (size_t)blockIdx.z * K * N;
  int m0 = blockIdx.y * BM, n0 = blockIdx.x * BN;
  __shared__ unsigned short As[BM][40];    // stride 40 -> 16B-aligned rows, <=2-way banks
  __shared__ unsigned short Bs[BK][136];   // stride 136 -> 16B-aligned rows
  int t = threadIdx.x;
  int wave = t >> 6, lane = t & 63;
  int wr = wave >> 1, wc = wave & 1;
  int l16 = lane & 15, quad = lane >> 4;
  f32x4 z = {0.f, 0.f, 0.f, 0.f};
  f32x4 acc[2][4];
  #pragma unroll
  for (int i = 0; i < 2; ++i)
    #pragma unroll
    for (int j = 0; j < 4; ++j) acc[i][j] = z;

  int kTiles = (K + BK - 1) / BK;
  for (int kt = 0; kt < kTiles; ++kt){
    int k0 = kt * BK;
    { // stage A tile 64x32 (guarded, handles M=1020 / K=510 tails)
      int m = t >> 2, kk = (t & 3) * 8;
      int gm = m0 + m;
      #pragma unroll
      for (int j = 0; j < 4; ++j){
        unsigned int v = 0u;
        int gk = k0 + kk + 2 * j;             // K always even -> pair-guard ok
        if (gm < M && gk < K) v = *(const unsigned int*)(A + (size_t)gm * K + gk);
        *(unsigned int*)&As[m][kk + 2 * j] = v;
      }
    }
    { // stage B tile 32x128 (coalesced 16B loads)
      int nn = (t & 15) * 8;
      #pragma unroll
      for (int h2 = 0; h2 < 2; ++h2){
        int r = (t >> 4) + h2 * 16;
        int gk = k0 + r;
        uint4 v; v.x = v.y = v.z = v.w = 0u;
        if (gk < K) v = *(const uint4*)(Bp + (size_t)gk * N + n0 + nn);
        *(uint4*)&Bs[r][nn] = v;
      }
    }
    __syncthreads();
    short8 af[2];
    #pragma unroll
    for (int mt = 0; mt < 2; ++mt)
      af[mt] = *(const short8*)&As[wr * 32 + mt * 16 + l16][quad * 8];
    #pragma unroll
    for (int nt = 0; nt < 4; ++nt){
      int n = wc * 64 + nt * 16 + l16;
      short8 bf;
      #pragma unroll
      for (int j = 0; j < 8; ++j) bf[j] = (short)Bs[quad * 8 + j][n];
      #pragma unroll
      for (int mt = 0; mt < 2; ++mt)
        acc[mt][nt] = __builtin_amdgcn_mfma_f32_16x16x32_bf16(af[mt], bf, acc[mt][nt], 0, 0, 0);
    }
    __syncthreads();
  }
  // epilogue: +bias (+residual), store bf16 or fp32
  #pragma unroll
  for (int mt = 0; mt < 2; ++mt)
    #pragma unroll
    for (int nt = 0; nt < 4; ++nt){
      int n = n0 + wc * 64 + nt * 16 + l16;
      #pragma unroll
      for (int r = 0; r < 4; ++r){
        int m = m0 + wr * 32 + mt * 16 + quad * 4 + r;
        if (m < M){
          float v = acc[mt][nt][r] + bias[m];
          size_t idx = (size_t)blockIdx.z * M * N + (size_t)m * N + n;
          if (resid) v += resid[idx];
          if (ofp32) ((float*)outp)[idx] = v;
          else       ((unsigned short*)outp)[idx] = f2bf(v);
        }
      }
    }
}

// ---------------- depthwise 3x3 (SAME, zero pad) + bias, bf16->bf16 ----------------
__global__ __launch_bounds__(256) void dw3_k(const unsigned short* __restrict__ in,
                                             const float* __restrict__ w, const float* __restrict__ bias,
                                             unsigned short* __restrict__ out, int C){
  int zc = blockIdx.y;
  int b = zc / C, c = zc - b * C;
  const unsigned short* im = in + ((size_t)(b * C + c)) * HW;
  int t = threadIdx.x;
  int row = blockIdx.x * 2 + (t >> 7), col = t & 127;
  const float* wc = w + c * 9;
  float acc = bias[c];
  #pragma unroll
  for (int dy = -1; dy <= 1; ++dy){
    int r = row + dy;
    if ((unsigned)r < 128u){
      #pragma unroll
      for (int dx = -1; dx <= 1; ++dx){
        int cc = col + dx;
        if ((unsigned)cc < 128u) acc += wc[(dy + 1) * 3 + dx + 1] * bf2f(im[r * 128 + cc]);
      }
    }
  }
  out[((size_t)(b * C + c)) * HW + row * 128 + col] = f2bf(acc);
}

// ---------------- GDFN: g = dw(h[0:510]) * dw(h[510:1020]) ----------------
__global__ __launch_bounds__(256) void dwgate_k(const unsigned short* __restrict__ h,
                                                const float* __restrict__ w, const float* __restrict__ bias,
                                                unsigned short* __restrict__ g){
  int zc = blockIdx.y;
  int b = zc / 510, j = zc - b * 510;
  int t = threadIdx.x;
  int row = blockIdx.x * 2 + (t >> 7), col = t & 127;
  const unsigned short* im1 = h + ((size_t)(b * 1020 + j)) * HW;
  const unsigned short* im2 = h + ((size_t)(b * 1020 + 510 + j)) * HW;
  const float* w1 = w + j * 9;
  const float* w2 = w + (510 + j) * 9;
  float a1 = bias[j], a2 = bias[510 + j];
  #pragma unroll
  for (int dy = -1; dy <= 1; ++dy){
    int r = row + dy;
    if ((unsigned)r < 128u){
      #pragma unroll
      for (int dx = -1; dx <= 1; ++dx){
        int cc = col + dx;
        if ((unsigned)cc < 128u){
          int idx = r * 128 + cc;
          int wi = (dy + 1) * 3 + dx + 1;
          a1 += w1[wi] * bf2f(im1[idx]);
          a2 += w2[wi] * bf2f(im2[idx]);
        }
      }
    }
  }
  g[((size_t)(b * 510 + j)) * HW + row * 128 + col] = f2bf(a1 * a2);
}

// ---------------- L2 row norms of q,k rows (len 16384) ----------------
__global__ __launch_bounds__(256) void rownorm_k(const unsigned short* __restrict__ qkv_dw,
                                                 float* __restrict__ qn, float* __restrict__ kn){
  int rid = blockIdx.x;           // 0..1535
  int isK = rid >= 768;
  int r = rid & 767;
  int b = r / 192, ch = r - b * 192;
  const unsigned short* row = qkv_dw + ((size_t)b * 576 + (isK ? 192 : 0) + ch) * HW;
  int t = threadIdx.x;
  float s = 0.f;
  for (int it = 0; it < 8; ++it){
    uint4 v = *(const uint4*)(row + (size_t)(it * 256 + t) * 8);
    const unsigned short* u = (const unsigned short*)&v;
    #pragma unroll
    for (int j = 0; j < 8; ++j){ float f = bf2f(u[j]); s += f * f; }
  }
  #pragma unroll
  for (int off = 32; off; off >>= 1) s += __shfl_down(s, off);
  __shared__ float red[4];
  if ((t & 63) == 0) red[t >> 6] = s;
  __syncthreads();
  if (t == 0) (isK ? kn : qn)[r] = sqrtf(red[0] + red[1] + red[2] + red[3]);
}

// ---------------- QK^T via MFMA, K-split partials. grid (32 ksplit, 32 bh), 1 wave ----------------
__global__ __launch_bounds__(64) void qk_k(const unsigned short* __restrict__ qkv_dw, float* __restrict__ part){
  int bh = blockIdx.y; int b = bh >> 3, h = bh & 7;
  int ks = blockIdx.x;
  int lane = threadIdx.x;
  int l16 = lane & 15, quad = lane >> 4;
  const unsigned short* qb = qkv_dw + ((size_t)b * 576 + h * 24) * HW;
  const unsigned short* kb = qkv_dw + ((size_t)b * 576 + 192 + h * 24) * HW;
  f32x4 z = {0.f, 0.f, 0.f, 0.f};
  f32x4 a00 = z, a01 = z, a10 = z, a11 = z;
  for (int st = 0; st < 16; ++st){
    int k0 = ks * 512 + st * 32 + quad * 8;
    short8 qa0 = *(const short8*)(qb + (size_t)l16 * HW + k0);
    short8 qa1 = *(const short8*)(qb + (size_t)(l16 + 16) * HW + k0);
    short8 kb0 = *(const short8*)(kb + (size_t)l16 * HW + k0);
    short8 kb1 = *(const short8*)(kb + (size_t)(l16 + 16) * HW + k0);
    a00 = __builtin_amdgcn_mfma_f32_16x16x32_bf16(qa0, kb0, a00, 0, 0, 0);
    a01 = __builtin_amdgcn_mfma_f32_16x16x32_bf16(qa0, kb1, a01, 0, 0, 0);
    a10 = __builtin_amdgcn_mfma_f32_16x16x32_bf16(qa1, kb0, a10, 0, 0, 0);
    a11 = __builtin_amdgcn_mfma_f32_16x16x32_bf16(qa1, kb1, a11, 0, 0, 0);
  }
  float* pp = part + ((size_t)bh * 32 + ks) * 576;
  #pragma unroll
  for (int r = 0; r < 4; ++r){
    int c0 = quad * 4 + r, c1 = 16 + quad * 4 + r;
    int d0 = l16, d1 = 16 + l16;
    if (c0 < 24 && d0 < 24) pp[c0 * 24 + d0] = a00[r];
    if (c0 < 24 && d1 < 24) pp[c0 * 24 + d1] = a01[r];
    if (c1 < 24 && d0 < 24) pp[c1 * 24 + d0] = a10[r];
    if (c1 < 24 && d1 < 24) pp[c1 * 24 + d1] = a11[r];
  }
}

// ---------------- reduce partials, scale by temp/(|q||k|), softmax over d ----------------
__global__ void softmax_k(const float* __restrict__ part, const float* __restrict__ qn,
                          const float* __restrict__ kn, const float* __restrict__ temp,
                          float* __restrict__ attn){
  int bh = blockIdx.x; int b = bh >> 3, h = bh & 7;
  int c = threadIdx.x;
  if (c >= 24) return;
  float tmp = temp[h];
  float qv = fmaxf(qn[b * 192 + h * 24 + c], 1e-12f);
  float row[24];
  #pragma unroll
  for (int d = 0; d < 24; ++d){
    float s = 0.f;
    for (int sp = 0; sp < 32; ++sp) s += part[((size_t)bh * 32 + sp) * 576 + c * 24 + d];
    float kv = fmaxf(kn[b * 192 + h * 24 + d], 1e-12f);
    row[d] = s * tmp / (qv * kv);
  }
  float mx = row[0];
  #pragma unroll
  for (int d = 1; d < 24; ++d) mx = fmaxf(mx, row[d]);
  float sum = 0.f;
  #pragma unroll
  for (int d = 0; d < 24; ++d){ row[d] = expf(row[d] - mx); sum += row[d]; }
  float inv = 1.f / sum;
  #pragma unroll
  for (int d = 0; d < 24; ++d) attn[(size_t)bh * 576 + c * 24 + d] = row[d] * inv;
}

// ---------------- out[c][p] = sum_d attn[c][d] * v[d][p] ----------------
__global__ __launch_bounds__(256) void av_k(const float* __restrict__ attn,
                                            const unsigned short* __restrict__ qkv_dw,
                                            unsigned short* __restrict__ o){
  int bh = blockIdx.y; int b = bh >> 3, h = bh & 7;
  __shared__ float As[576];
  int t = threadIdx.x;
  for (int i = t; i < 576; i += 256) As[i] = attn[(size_t)bh * 576 + i];
  __syncthreads();
  int p = blockIdx.x * 256 + t;
  const unsigned short* vb = qkv_dw + ((size_t)b * 576 + 384 + h * 24) * HW + p;
  float acc[24];
  #pragma unroll
  for (int c = 0; c < 24; ++c) acc[c] = 0.f;
  #pragma unroll
  for (int d = 0; d < 24; ++d){
    float vv = bf2f(vb[(size_t)d * HW]);
    #pragma unroll
    for (int c = 0; c < 24; ++c) acc[c] += As[c * 24 + d] * vv;
  }
  unsigned short* ob = o + ((size_t)b * 192 + h * 24) * HW + p;
  #pragma unroll
  for (int c = 0; c < 24; ++c) ob[(size_t)c * HW] = f2bf(acc[c]);
}

extern "C" void kernel_launch(void* const* d_in, const int* in_sizes, int n_in,
                              void* d_out, int out_size, void* d_ws, size_t ws_size,
                              hipStream_t stream){
  (void)in_sizes; (void)n_in; (void)out_size; (void)ws_size;
  const float* x        = (const float*)d_in[0];
  const float* t_emb    = (const float*)d_in[1];
  const float* n1_w     = (const float*)d_in[2];
  const float* n1_b     = (const float*)d_in[3];
  const float* temp     = (const float*)d_in[4];
  const float* a_qkv_w  = (const float*)d_in[5];
  const float* a_qkv_b  = (const float*)d_in[6];
  const float* a_dw_w   = (const float*)d_in[7];
  const float* a_dw_b   = (const float*)d_in[8];
  const float* a_proj_w = (const float*)d_in[9];
  const float* a_proj_b = (const float*)d_in[10];
  const float* a_t_w    = (const float*)d_in[11];
  const float* a_t_b    = (const float*)d_in[12];
  const float* n2_w     = (const float*)d_in[13];
  const float* n2_b     = (const float*)d_in[14];
  const float* f_c1_w   = (const float*)d_in[15];
  const float* f_c1_b   = (const float*)d_in[16];
  const float* f_dw_w   = (const float*)d_in[17];
  const float* f_dw_b   = (const float*)d_in[18];
  const float* f_c2_w   = (const float*)d_in[19];
  const float* f_c2_b   = (const float*)d_in[20];
  const float* f_t_w    = (const float*)d_in[21];
  const float* f_t_b    = (const float*)d_in[22];
  float* out = (float*)d_out;
  char* ws = (char*)d_ws;

  // phase-overlapped workspace layout (needs ~229 MB)
  unsigned short* y_buf = (unsigned short*)(ws + 0);          // 25.2MB  y1 / y2
  unsigned short* qkv   = (unsigned short*)(ws + 25165824);   // 75.5MB  (stage A)
  unsigned short* hbuf  = (unsigned short*)(ws + 25165824);   // 133.7MB (stage B, reuses qkv+qkvd)
  unsigned short* qkvd  = (unsigned short*)(ws + 100663296);  // 75.5MB
  unsigned short* obuf  = (unsigned short*)(ws + 176160768);  // 25.2MB (dead before g written)
  unsigned short* gbuf  = (unsigned short*)(ws + 158859264);  // 66.8MB
  const size_t S = 225705984;
  float* mod_a = (float*)(ws + S);
  float* mod_f = (float*)(ws + S + 8192);
  float* qn    = (float*)(ws + S + 16384);
  float* kn    = (float*)(ws + S + 20480);
  float* part  = (float*)(ws + S + 24576);        // 32*32*576*4 = 2359296
  float* attn  = (float*)(ws + S + 2383872);      // 73728
  unsigned short* Wq = (unsigned short*)(ws + S + 2457600);
  unsigned short* Wp = (unsigned short*)(ws + S + 2678784);
  unsigned short* W1 = (unsigned short*)(ws + S + 2752512);
  unsigned short* W2 = (unsigned short*)(ws + S + 3144192);

  castw_k<<<dim3((110592 + 255) / 256), 256, 0, stream>>>(a_qkv_w, Wq, 110592);
  castw_k<<<dim3((36864 + 255) / 256), 256, 0, stream>>>(a_proj_w, Wp, 36864);
  castw_k<<<dim3((195840 + 255) / 256), 256, 0, stream>>>(f_c1_w, W1, 195840);
  castw_k<<<dim3((97920 + 255) / 256), 256, 0, stream>>>(f_c2_w, W2, 97920);
  modk<<<dim3(3, 4, 2), 128, 0, stream>>>(t_emb, a_t_w, a_t_b, f_t_w, f_t_b, mod_a, mod_f);

  // ---- MDTA branch ----
  lnmod_k<<<dim3(256, 4), 256, 0, stream>>>(x, n1_w, n1_b, mod_a, y_buf);
  gemm_k<<<dim3(128, 9, 4), 256, 0, stream>>>(Wq, y_buf, a_qkv_b, nullptr, qkv, 576, 192, 0);
  dw3_k<<<dim3(64, 2304), 256, 0, stream>>>(qkv, a_dw_w, a_dw_b, qkvd, 576);
  rownorm_k<<<1536, 256, 0, stream>>>(qkvd, qn, kn);
  qk_k<<<dim3(32, 32), 64, 0, stream>>>(qkvd, part);
  softmax_k<<<32, 64, 0, stream>>>(part, qn, kn, temp, attn);
  av_k<<<dim3(64, 32), 256, 0, stream>>>(attn, qkvd, obuf);
  gemm_k<<<dim3(128, 3, 4), 256, 0, stream>>>(Wp, obuf, a_proj_b, x, out, 192, 192, 1); // out = x1

  // ---- GDFN branch ----
  lnmod_k<<<dim3(256, 4), 256, 0, stream>>>(out, n2_w, n2_b, mod_f, y_buf);
  gemm_k<<<dim3(128, 16, 4), 256, 0, stream>>>(W1, y_buf, f_c1_b, nullptr, hbuf, 1020, 192, 0);
  dwgate_k<<<dim3(64, 2040), 256, 0, stream>>>(hbuf, f_dw_w, f_dw_b, gbuf);
  gemm_k<<<dim3(128, 3, 4), 256, 0, stream>>>(W2, gbuf, f_c2_b, out, out, 192, 510, 1);
}

// Round 2
// 821.122 us; speedup vs baseline: 1.3592x; 1.3592x over previous
//
#include <hip/hip_runtime.h>
#include <math.h>

#define HW 16384

using short8 = __attribute__((ext_vector_type(8))) short;
using f32x4  = __attribute__((ext_vector_type(4))) float;

__device__ __forceinline__ float bf2f(unsigned short u){
  union { unsigned int i; float f; } x; x.i = ((unsigned int)u) << 16; return x.f;
}
__device__ __forceinline__ unsigned short f2bf(float f){
  union { float f; unsigned int i; } x; x.f = f;
  return (unsigned short)((x.i + 0x7FFFu + ((x.i >> 16) & 1u)) >> 16);
}

// ---------------- weight fp32 -> bf16 ----------------
__global__ void castw_k(const float* __restrict__ in, unsigned short* __restrict__ out, int n){
  int i = blockIdx.x * 256 + threadIdx.x;
  if (i < n) out[i] = f2bf(in[i]);
}

// ---------------- time modulation: silu(t_emb) @ W^T + b ----------------
__global__ void modk(const float* __restrict__ t_emb,
                     const float* __restrict__ aw, const float* __restrict__ ab,
                     const float* __restrict__ fw, const float* __restrict__ fb,
                     float* __restrict__ mod_a, float* __restrict__ mod_f){
  int o = blockIdx.x * 128 + threadIdx.x;   // 0..383
  int b = blockIdx.y;
  const float* w  = blockIdx.z ? fw : aw;
  const float* bi = blockIdx.z ? fb : ab;
  float* outp     = blockIdx.z ? mod_f : mod_a;
  const float* te = t_emb + b * 256;
  float acc = bi[o];
  for (int k = 0; k < 256; ++k){
    float u = te[k];
    float s = u / (1.f + expf(-u));
    acc += s * w[o * 256 + k];
  }
  outp[b * 384 + o] = acc;
}

// ---------------- channel LayerNorm (ddof=1, std+eps) + modulate -> bf16 ----------------
// block = 256 = 64 pixels x 4 channel-groups(48ch). grid (256, B)
__global__ __launch_bounds__(256) void lnmod_k(const float* __restrict__ x,
                                               const float* __restrict__ nw, const float* __restrict__ nb,
                                               const float* __restrict__ mod, unsigned short* __restrict__ y){
  int b = blockIdx.y;
  int t = threadIdx.x;
  int pl = t & 63, cg = t >> 6;
  int p = blockIdx.x * 64 + pl;
  const float* xb = x + (size_t)b * 192 * HW + p;
  float s = 0.f, s2 = 0.f;
  #pragma unroll 8
  for (int c = cg * 48; c < cg * 48 + 48; ++c){
    float v = xb[(size_t)c * HW]; s += v; s2 += v * v;
  }
  __shared__ float rs[4][64], rq[4][64];
  rs[cg][pl] = s; rq[cg][pl] = s2;
  __syncthreads();
  float S  = rs[0][pl] + rs[1][pl] + rs[2][pl] + rs[3][pl];
  float S2 = rq[0][pl] + rq[1][pl] + rq[2][pl] + rq[3][pl];
  float mean = S * (1.f / 192.f);
  float var  = (S2 - S * mean) * (1.f / 191.f);
  float rinv = 1.f / (sqrtf(fmaxf(var, 0.f)) + 1e-6f);
  const float* mo = mod + b * 384;
  unsigned short* yb = y + (size_t)b * 192 * HW + p;
  #pragma unroll 8
  for (int c = cg * 48; c < cg * 48 + 48; ++c){
    float v = xb[(size_t)c * HW];
    float ln = nw[c] * ((v - mean) * rinv) + nb[c];
    yb[(size_t)c * HW] = f2bf(ln * (1.f + mo[c]) + mo[192 + c]);
  }
}

// ---------------- bf16 MFMA GEMM: out[b][m][n] = W[m][k] @ Act[b][k][n] + bias ----------------
#define BM 64
#define BN 128
#define BK 32
__global__ __launch_bounds__(256) void gemm_k(const unsigned short* __restrict__ A,
                                              const unsigned short* __restrict__ Bact,
                                              const float* __restrict__ bias,
                                              const float* resid, void* outp,
                                              int M, int K, int ofp32){
  const int N = HW;
  const unsigned short* Bp = Bact + (size_t)blockIdx.z * K * N;
  int m0 = blockIdx.y * BM, n0 = blockIdx.x * BN;
  __shared__ unsigned short As[BM][40];    // stride 40 -> 16B-aligned rows, <=2-way banks
  __shared__ unsigned short Bs[BK][136];   // stride 136 -> 16B-aligned rows
  int t = threadIdx.x;
  int wave = t >> 6, lane = t & 63;
  int wr = wave >> 1, wc = wave & 1;
  int l16 = lane & 15, quad = lane >> 4;
  f32x4 z = {0.f, 0.f, 0.f, 0.f};
  f32x4 acc[2][4];
  #pragma unroll
  for (int i = 0; i < 2; ++i)
    #pragma unroll
    for (int j = 0; j < 4; ++j) acc[i][j] = z;

  int kTiles = (K + BK - 1) / BK;
  for (int kt = 0; kt < kTiles; ++kt){
    int k0 = kt * BK;
    { // stage A tile 64x32 (guarded, handles M=1020 / K=510 tails)
      int m = t >> 2, kk = (t & 3) * 8;
      int gm = m0 + m;
      #pragma unroll
      for (int j = 0; j < 4; ++j){
        unsigned int v = 0u;
        int gk = k0 + kk + 2 * j;             // K always even -> pair-guard ok
        if (gm < M && gk < K) v = *(const unsigned int*)(A + (size_t)gm * K + gk);
        *(unsigned int*)&As[m][kk + 2 * j] = v;
      }
    }
    { // stage B tile 32x128 (coalesced 16B loads)
      int nn = (t & 15) * 8;
      #pragma unroll
      for (int h2 = 0; h2 < 2; ++h2){
        int r = (t >> 4) + h2 * 16;
        int gk = k0 + r;
        uint4 v; v.x = v.y = v.z = v.w = 0u;
        if (gk < K) v = *(const uint4*)(Bp + (size_t)gk * N + n0 + nn);
        *(uint4*)&Bs[r][nn] = v;
      }
    }
    __syncthreads();
    short8 af[2];
    #pragma unroll
    for (int mt = 0; mt < 2; ++mt)
      af[mt] = *(const short8*)&As[wr * 32 + mt * 16 + l16][quad * 8];
    #pragma unroll
    for (int nt = 0; nt < 4; ++nt){
      int n = wc * 64 + nt * 16 + l16;
      short8 bf;
      #pragma unroll
      for (int j = 0; j < 8; ++j) bf[j] = (short)Bs[quad * 8 + j][n];
      #pragma unroll
      for (int mt = 0; mt < 2; ++mt)
        acc[mt][nt] = __builtin_amdgcn_mfma_f32_16x16x32_bf16(af[mt], bf, acc[mt][nt], 0, 0, 0);
    }
    __syncthreads();
  }
  // epilogue: +bias (+residual), store bf16 or fp32
  #pragma unroll
  for (int mt = 0; mt < 2; ++mt)
    #pragma unroll
    for (int nt = 0; nt < 4; ++nt){
      int n = n0 + wc * 64 + nt * 16 + l16;
      #pragma unroll
      for (int r = 0; r < 4; ++r){
        int m = m0 + wr * 32 + mt * 16 + quad * 4 + r;
        if (m < M){
          float v = acc[mt][nt][r] + bias[m];
          size_t idx = (size_t)blockIdx.z * M * N + (size_t)m * N + n;
          if (resid) v += resid[idx];
          if (ofp32) ((float*)outp)[idx] = v;
          else       ((unsigned short*)outp)[idx] = f2bf(v);
        }
      }
    }
}

// ---------------- depthwise 3x3 (SAME) + bias + fused q/k sum-of-squares ----------------
// block stages a 66-row x 128-col slab of one channel in LDS; each thread does
// 4 segments of 8 pixels. grid (2, B*C)
__global__ __launch_bounds__(256) void dw3_k(const unsigned short* __restrict__ in,
                                             const float* __restrict__ w, const float* __restrict__ bias,
                                             unsigned short* __restrict__ out, int C,
                                             float* __restrict__ qn, float* __restrict__ kn){
  __shared__ unsigned short tile[66 * 128];
  __shared__ float red[4];
  int zc = blockIdx.y;
  int b = zc / C, c = zc - b * C;
  int r0 = blockIdx.x * 64;
  const unsigned short* im = in + ((size_t)(b * C + c)) * HW;
  unsigned short* om = out + ((size_t)(b * C + c)) * HW;
  int t = threadIdx.x;
  #pragma unroll
  for (int i = 0; i < 5; ++i){
    int idx = t + 256 * i;
    if (idx < 1056){
      int lr = idx >> 4, lc = (idx & 15) * 8;
      int gr = r0 - 1 + lr;
      uint4 v = {0u, 0u, 0u, 0u};
      if ((unsigned)gr < 128u) v = *(const uint4*)(im + gr * 128 + lc);
      *(uint4*)&tile[lr * 128 + lc] = v;
    }
  }
  __syncthreads();
  const float* wc = w + c * 9;
  float W[9];
  #pragma unroll
  for (int i = 0; i < 9; ++i) W[i] = wc[i];
  float bs = bias[c];
  float ssq = 0.f;
  #pragma unroll
  for (int i = 0; i < 4; ++i){
    int seg = t + 256 * i;
    int orow = seg >> 4, sc = (seg & 15) * 8;
    float acc[8];
    #pragma unroll
    for (int j = 0; j < 8; ++j) acc[j] = bs;
    #pragma unroll
    for (int rr = 0; rr < 3; ++rr){
      const unsigned short* rp = &tile[(orow + rr) * 128 + sc];
      float v[10];
      v[0] = (sc > 0) ? bf2f(rp[-1]) : 0.f;
      uint4 m = *(const uint4*)rp;
      const unsigned short* mu = (const unsigned short*)&m;
      #pragma unroll
      for (int j = 0; j < 8; ++j) v[j + 1] = bf2f(mu[j]);
      v[9] = (sc < 120) ? bf2f(rp[8]) : 0.f;
      float wa = W[rr * 3], wb = W[rr * 3 + 1], wd = W[rr * 3 + 2];
      #pragma unroll
      for (int j = 0; j < 8; ++j) acc[j] += wa * v[j] + wb * v[j + 1] + wd * v[j + 2];
    }
    unsigned short ob[8];
    #pragma unroll
    for (int j = 0; j < 8; ++j){
      ob[j] = f2bf(acc[j]);
      float q = bf2f(ob[j]);
      ssq += q * q;
    }
    *(uint4*)(om + (r0 + orow) * 128 + sc) = *(uint4*)ob;
  }
  if (c < 384){   // block-uniform branch
    #pragma unroll
    for (int off = 32; off; off >>= 1) ssq += __shfl_down(ssq, off);
    if ((t & 63) == 0) red[t >> 6] = ssq;
    __syncthreads();
    if (t == 0){
      float s = red[0] + red[1] + red[2] + red[3];
      float* dst = (c < 192) ? (qn + b * 192 + c) : (kn + b * 192 + c - 192);
      atomicAdd(dst, s);
    }
  }
}

// ---------------- GDFN: g = dw(h[0:510]) * dw(h[510:1020]), LDS slab version ----------------
__global__ __launch_bounds__(256) void dwgate_k(const unsigned short* __restrict__ h,
                                                const float* __restrict__ w, const float* __restrict__ bias,
                                                unsigned short* __restrict__ g){
  __shared__ unsigned short tile[2 * 66 * 128];
  int zc = blockIdx.y;
  int b = zc / 510, j = zc - b * 510;
  int r0 = blockIdx.x * 64;
  const unsigned short* im1 = h + ((size_t)(b * 1020 + j)) * HW;
  const unsigned short* im2 = h + ((size_t)(b * 1020 + 510 + j)) * HW;
  int t = threadIdx.x;
  #pragma unroll
  for (int i = 0; i < 9; ++i){
    int idx = t + 256 * i;
    if (idx < 2112){
      int img = (idx >= 1056) ? 1 : 0;
      int li = idx - img * 1056;
      int lr = li >> 4, lc = (li & 15) * 8;
      int gr = r0 - 1 + lr;
      uint4 v = {0u, 0u, 0u, 0u};
      const unsigned short* im = img ? im2 : im1;
      if ((unsigned)gr < 128u) v = *(const uint4*)(im + gr * 128 + lc);
      *(uint4*)&tile[img * 8448 + lr * 128 + lc] = v;
    }
  }
  __syncthreads();
  float W1[9], W2[9];
  #pragma unroll
  for (int i = 0; i < 9; ++i){ W1[i] = w[j * 9 + i]; W2[i] = w[(510 + j) * 9 + i]; }
  float b1 = bias[j], b2 = bias[510 + j];
  unsigned short* gm = g + ((size_t)(b * 510 + j)) * HW;
  #pragma unroll
  for (int i = 0; i < 4; ++i){
    int seg = t + 256 * i;
    int orow = seg >> 4, sc = (seg & 15) * 8;
    float a1[8], a2[8];
    #pragma unroll
    for (int q = 0; q < 8; ++q){ a1[q] = b1; a2[q] = b2; }
    #pragma unroll
    for (int rr = 0; rr < 3; ++rr){
      #pragma unroll
      for (int img = 0; img < 2; ++img){
        const unsigned short* rp = &tile[img * 8448 + (orow + rr) * 128 + sc];
        float v[10];
        v[0] = (sc > 0) ? bf2f(rp[-1]) : 0.f;
        uint4 m = *(const uint4*)rp;
        const unsigned short* mu = (const unsigned short*)&m;
        #pragma unroll
        for (int q = 0; q < 8; ++q) v[q + 1] = bf2f(mu[q]);
        v[9] = (sc < 120) ? bf2f(rp[8]) : 0.f;
        const float* ww = img ? W2 : W1;
        float* aa = img ? a2 : a1;
        float wa = ww[rr * 3], wb = ww[rr * 3 + 1], wd = ww[rr * 3 + 2];
        #pragma unroll
        for (int q = 0; q < 8; ++q) aa[q] += wa * v[q] + wb * v[q + 1] + wd * v[q + 2];
      }
    }
    unsigned short ob[8];
    #pragma unroll
    for (int q = 0; q < 8; ++q) ob[q] = f2bf(a1[q] * a2[q]);
    *(uint4*)(gm + (r0 + orow) * 128 + sc) = *(uint4*)ob;
  }
}

// ---------------- QK^T via MFMA, K-split partials. grid (32 ksplit, 32 bh), 1 wave ----------------
__global__ __launch_bounds__(64) void qk_k(const unsigned short* __restrict__ qkv_dw, float* __restrict__ part){
  int bh = blockIdx.y; int b = bh >> 3, h = bh & 7;
  int ks = blockIdx.x;
  int lane = threadIdx.x;
  int l16 = lane & 15, quad = lane >> 4;
  const unsigned short* qb = qkv_dw + ((size_t)b * 576 + h * 24) * HW;
  const unsigned short* kb = qkv_dw + ((size_t)b * 576 + 192 + h * 24) * HW;
  f32x4 z = {0.f, 0.f, 0.f, 0.f};
  f32x4 a00 = z, a01 = z, a10 = z, a11 = z;
  for (int st = 0; st < 16; ++st){
    int k0 = ks * 512 + st * 32 + quad * 8;
    short8 qa0 = *(const short8*)(qb + (size_t)l16 * HW + k0);
    short8 qa1 = *(const short8*)(qb + (size_t)(l16 + 16) * HW + k0);
    short8 kb0 = *(const short8*)(kb + (size_t)l16 * HW + k0);
    short8 kb1 = *(const short8*)(kb + (size_t)(l16 + 16) * HW + k0);
    a00 = __builtin_amdgcn_mfma_f32_16x16x32_bf16(qa0, kb0, a00, 0, 0, 0);
    a01 = __builtin_amdgcn_mfma_f32_16x16x32_bf16(qa0, kb1, a01, 0, 0, 0);
    a10 = __builtin_amdgcn_mfma_f32_16x16x32_bf16(qa1, kb0, a10, 0, 0, 0);
    a11 = __builtin_amdgcn_mfma_f32_16x16x32_bf16(qa1, kb1, a11, 0, 0, 0);
  }
  float* pp = part + ((size_t)bh * 32 + ks) * 576;
  #pragma unroll
  for (int r = 0; r < 4; ++r){
    int c0 = quad * 4 + r, c1 = 16 + quad * 4 + r;
    int d0 = l16, d1 = 16 + l16;
    if (c0 < 24 && d0 < 24) pp[c0 * 24 + d0] = a00[r];
    if (c0 < 24 && d1 < 24) pp[c0 * 24 + d1] = a01[r];
    if (c1 < 24 && d0 < 24) pp[c1 * 24 + d0] = a10[r];
    if (c1 < 24 && d1 < 24) pp[c1 * 24 + d1] = a11[r];
  }
}

// ---------------- reduce partials, scale by temp/(|q||k|), softmax over d ----------------
// qn/kn now hold SUM OF SQUARES (fused into dw3_k) -> sqrt here
__global__ void softmax_k(const float* __restrict__ part, const float* __restrict__ qn,
                          const float* __restrict__ kn, const float* __restrict__ temp,
                          float* __restrict__ attn){
  int bh = blockIdx.x; int b = bh >> 3, h = bh & 7;
  int c = threadIdx.x;
  if (c >= 24) return;
  float tmp = temp[h];
  float qv = fmaxf(sqrtf(qn[b * 192 + h * 24 + c]), 1e-12f);
  float row[24];
  #pragma unroll
  for (int d = 0; d < 24; ++d){
    float s = 0.f;
    for (int sp = 0; sp < 32; ++sp) s += part[((size_t)bh * 32 + sp) * 576 + c * 24 + d];
    float kv = fmaxf(sqrtf(kn[b * 192 + h * 24 + d]), 1e-12f);
    row[d] = s * tmp / (qv * kv);
  }
  float mx = row[0];
  #pragma unroll
  for (int d = 1; d < 24; ++d) mx = fmaxf(mx, row[d]);
  float sum = 0.f;
  #pragma unroll
  for (int d = 0; d < 24; ++d){ row[d] = expf(row[d] - mx); sum += row[d]; }
  float inv = 1.f / sum;
  #pragma unroll
  for (int d = 0; d < 24; ++d) attn[(size_t)bh * 576 + c * 24 + d] = row[d] * inv;
}

// ---------------- out[c][p] = sum_d attn[c][d] * v[d][p] ----------------
__global__ __launch_bounds__(256) void av_k(const float* __restrict__ attn,
                                            const unsigned short* __restrict__ qkv_dw,
                                            unsigned short* __restrict__ o){
  int bh = blockIdx.y; int b = bh >> 3, h = bh & 7;
  __shared__ float As[576];
  int t = threadIdx.x;
  for (int i = t; i < 576; i += 256) As[i] = attn[(size_t)bh * 576 + i];
  __syncthreads();
  int p = blockIdx.x * 256 + t;
  const unsigned short* vb = qkv_dw + ((size_t)b * 576 + 384 + h * 24) * HW + p;
  float acc[24];
  #pragma unroll
  for (int c = 0; c < 24; ++c) acc[c] = 0.f;
  #pragma unroll
  for (int d = 0; d < 24; ++d){
    float vv = bf2f(vb[(size_t)d * HW]);
    #pragma unroll
    for (int c = 0; c < 24; ++c) acc[c] += As[c * 24 + d] * vv;
  }
  unsigned short* ob = o + ((size_t)b * 192 + h * 24) * HW + p;
  #pragma unroll
  for (int c = 0; c < 24; ++c) ob[(size_t)c * HW] = f2bf(acc[c]);
}

extern "C" void kernel_launch(void* const* d_in, const int* in_sizes, int n_in,
                              void* d_out, int out_size, void* d_ws, size_t ws_size,
                              hipStream_t stream){
  (void)in_sizes; (void)n_in; (void)out_size; (void)ws_size;
  const float* x        = (const float*)d_in[0];
  const float* t_emb    = (const float*)d_in[1];
  const float* n1_w     = (const float*)d_in[2];
  const float* n1_b     = (const float*)d_in[3];
  const float* temp     = (const float*)d_in[4];
  const float* a_qkv_w  = (const float*)d_in[5];
  const float* a_qkv_b  = (const float*)d_in[6];
  const float* a_dw_w   = (const float*)d_in[7];
  const float* a_dw_b   = (const float*)d_in[8];
  const float* a_proj_w = (const float*)d_in[9];
  const float* a_proj_b = (const float*)d_in[10];
  const float* a_t_w    = (const float*)d_in[11];
  const float* a_t_b    = (const float*)d_in[12];
  const float* n2_w     = (const float*)d_in[13];
  const float* n2_b     = (const float*)d_in[14];
  const float* f_c1_w   = (const float*)d_in[15];
  const float* f_c1_b   = (const float*)d_in[16];
  const float* f_dw_w   = (const float*)d_in[17];
  const float* f_dw_b   = (const float*)d_in[18];
  const float* f_c2_w   = (const float*)d_in[19];
  const float* f_c2_b   = (const float*)d_in[20];
  const float* f_t_w    = (const float*)d_in[21];
  const float* f_t_b    = (const float*)d_in[22];
  float* out = (float*)d_out;
  char* ws = (char*)d_ws;

  // phase-overlapped workspace layout (needs ~229 MB)
  unsigned short* y_buf = (unsigned short*)(ws + 0);          // 25.2MB  y1 / y2
  unsigned short* qkv   = (unsigned short*)(ws + 25165824);   // 75.5MB  (stage A)
  unsigned short* hbuf  = (unsigned short*)(ws + 25165824);   // 133.7MB (stage B, reuses qkv+qkvd)
  unsigned short* qkvd  = (unsigned short*)(ws + 100663296);  // 75.5MB
  unsigned short* obuf  = (unsigned short*)(ws + 176160768);  // 25.2MB (dead before g written)
  unsigned short* gbuf  = (unsigned short*)(ws + 158859264);  // 66.8MB
  const size_t S = 225705984;
  float* mod_a = (float*)(ws + S);
  float* mod_f = (float*)(ws + S + 8192);
  float* qn    = (float*)(ws + S + 16384);
  float* kn    = (float*)(ws + S + 20480);
  float* part  = (float*)(ws + S + 24576);        // 32*32*576*4 = 2359296
  float* attn  = (float*)(ws + S + 2383872);      // 73728
  unsigned short* Wq = (unsigned short*)(ws + S + 2457600);
  unsigned short* Wp = (unsigned short*)(ws + S + 2678784);
  unsigned short* W1 = (unsigned short*)(ws + S + 2752512);
  unsigned short* W2 = (unsigned short*)(ws + S + 3144192);

  castw_k<<<dim3((110592 + 255) / 256), 256, 0, stream>>>(a_qkv_w, Wq, 110592);
  castw_k<<<dim3((36864 + 255) / 256), 256, 0, stream>>>(a_proj_w, Wp, 36864);
  castw_k<<<dim3((195840 + 255) / 256), 256, 0, stream>>>(f_c1_w, W1, 195840);
  castw_k<<<dim3((97920 + 255) / 256), 256, 0, stream>>>(f_c2_w, W2, 97920);
  modk<<<dim3(3, 4, 2), 128, 0, stream>>>(t_emb, a_t_w, a_t_b, f_t_w, f_t_b, mod_a, mod_f);
  hipMemsetAsync(qn, 0, 2 * 768 * sizeof(float), stream);  // qn+kn contiguous

  // ---- MDTA branch ----
  lnmod_k<<<dim3(256, 4), 256, 0, stream>>>(x, n1_w, n1_b, mod_a, y_buf);
  gemm_k<<<dim3(128, 9, 4), 256, 0, stream>>>(Wq, y_buf, a_qkv_b, nullptr, qkv, 576, 192, 0);
  dw3_k<<<dim3(2, 2304), 256, 0, stream>>>(qkv, a_dw_w, a_dw_b, qkvd, 576, qn, kn);
  qk_k<<<dim3(32, 32), 64, 0, stream>>>(qkvd, part);
  softmax_k<<<32, 64, 0, stream>>>(part, qn, kn, temp, attn);
  av_k<<<dim3(64, 32), 256, 0, stream>>>(attn, qkvd, obuf);
  gemm_k<<<dim3(128, 3, 4), 256, 0, stream>>>(Wp, obuf, a_proj_b, x, out, 192, 192, 1); // out = x1

  // ---- GDFN branch ----
  lnmod_k<<<dim3(256, 4), 256, 0, stream>>>(out, n2_w, n2_b, mod_f, y_buf);
  gemm_k<<<dim3(128, 16, 4), 256, 0, stream>>>(W1, y_buf, f_c1_b, nullptr, hbuf, 1020, 192, 0);
  dwgate_k<<<dim3(2, 2040), 256, 0, stream>>>(hbuf, f_dw_w, f_dw_b, gbuf);
  gemm_k<<<dim3(128, 3, 4), 256, 0, stream>>>(W2, gbuf, f_c2_b, out, out, 192, 510, 1);
}

// Round 4
// 796.775 us; speedup vs baseline: 1.4008x; 1.0306x over previous
//
#include <hip/hip_runtime.h>
#include <math.h>

#define HW 16384

using short8 = __attribute__((ext_vector_type(8))) short;
using f32x4  = __attribute__((ext_vector_type(4))) float;

__device__ __forceinline__ float bf2f(unsigned short u){
  union { unsigned int i; float f; } x; x.i = ((unsigned int)u) << 16; return x.f;
}
__device__ __forceinline__ unsigned short f2bf(float f){
  union { float f; unsigned int i; } x; x.f = f;
  return (unsigned short)((x.i + 0x7FFFu + ((x.i >> 16) & 1u)) >> 16);
}

// ---------------- weight fp32 -> bf16 ----------------
__global__ void castw_k(const float* __restrict__ in, unsigned short* __restrict__ out, int n){
  int i = blockIdx.x * 256 + threadIdx.x;
  if (i < n) out[i] = f2bf(in[i]);
}
// cast + pad K: in [M][Kin] -> out [M][Kout], zeros beyond Kin
__global__ void castw_pad_k(const float* __restrict__ in, unsigned short* __restrict__ out,
                            int M, int Kin, int Kout){
  int i = blockIdx.x * 256 + threadIdx.x;
  if (i < M * Kout){
    int m = i / Kout, k = i - m * Kout;
    out[i] = (k < Kin) ? f2bf(in[m * Kin + k]) : (unsigned short)0;
  }
}

// ---------------- time modulation: silu(t_emb) @ W^T + b ----------------
__global__ void modk(const float* __restrict__ t_emb,
                     const float* __restrict__ aw, const float* __restrict__ ab,
                     const float* __restrict__ fw, const float* __restrict__ fb,
                     float* __restrict__ mod_a, float* __restrict__ mod_f){
  int o = blockIdx.x * 128 + threadIdx.x;   // 0..383
  int b = blockIdx.y;
  const float* w  = blockIdx.z ? fw : aw;
  const float* bi = blockIdx.z ? fb : ab;
  float* outp     = blockIdx.z ? mod_f : mod_a;
  const float* te = t_emb + b * 256;
  float acc = bi[o];
  for (int k = 0; k < 256; ++k){
    float u = te[k];
    float s = u / (1.f + expf(-u));
    acc += s * w[o * 256 + k];
  }
  outp[b * 384 + o] = acc;
}

// ---------------- channel LayerNorm (ddof=1, std+eps) + modulate -> bf16 PIXEL-MAJOR ----------------
// block = 256 = 64 pixels x 4 channel-groups(48ch). grid (256, B). y layout [b][p][192]
__global__ __launch_bounds__(256) void lnmod_k(const float* __restrict__ x,
                                               const float* __restrict__ nw, const float* __restrict__ nb,
                                               const float* __restrict__ mod, unsigned short* __restrict__ y){
  int b = blockIdx.y;
  int t = threadIdx.x;
  int pl = t & 63, cg = t >> 6;
  int p = blockIdx.x * 64 + pl;
  const float* xb = x + (size_t)b * 192 * HW + p;
  float s = 0.f, s2 = 0.f;
  #pragma unroll 8
  for (int c = cg * 48; c < cg * 48 + 48; ++c){
    float v = xb[(size_t)c * HW]; s += v; s2 += v * v;
  }
  __shared__ float rs[4][64], rq[4][64];
  rs[cg][pl] = s; rq[cg][pl] = s2;
  __syncthreads();
  float S  = rs[0][pl] + rs[1][pl] + rs[2][pl] + rs[3][pl];
  float S2 = rq[0][pl] + rq[1][pl] + rq[2][pl] + rq[3][pl];
  float mean = S * (1.f / 192.f);
  float var  = (S2 - S * mean) * (1.f / 191.f);
  float rinv = 1.f / (sqrtf(fmaxf(var, 0.f)) + 1e-6f);
  const float* mo = mod + b * 384;
  unsigned short buf[48];
  #pragma unroll 8
  for (int i = 0; i < 48; ++i){
    int c = cg * 48 + i;
    float v = xb[(size_t)c * HW];
    float ln = nw[c] * ((v - mean) * rinv) + nb[c];
    buf[i] = f2bf(ln * (1.f + mo[c]) + mo[192 + c]);
  }
  unsigned short* yb = y + ((size_t)b * HW + p) * 192 + cg * 48;
  #pragma unroll
  for (int i = 0; i < 6; ++i) *(uint4*)(yb + i * 8) = *(const uint4*)(buf + i * 8);
}

// ---------------- bf16 MFMA GEMM (both operands k-contiguous) ----------------
// out[b][m][n] = W[m][k] @ Act[b][n][k] + bias (+resid). K mult of 32, 16B rows.
// BM=64, BN=256, BK=32. 4 waves, each 64m x 64n quadrant.
__global__ __launch_bounds__(256) void gemm_tn(const unsigned short* __restrict__ A,
                                               const unsigned short* __restrict__ Bact,
                                               const float* __restrict__ bias,
                                               const float* resid, void* outp,
                                               int M, int K, int ofp32){
  const int N = HW;
  const unsigned short* Bp = Bact + (size_t)blockIdx.z * N * K;
  int m0 = blockIdx.x * 64, n0 = blockIdx.y * 256;
  __shared__ unsigned short As[64 * 32];    // row m: 64 B, k-contiguous
  __shared__ unsigned short Bs[256 * 32];   // row n: 64 B, k-contiguous
  int t = threadIdx.x;
  int w = t >> 6, lane = t & 63;
  int l16 = lane & 15, quad = lane >> 4;
  f32x4 z = {0.f, 0.f, 0.f, 0.f};
  f32x4 acc[4][4];
  #pragma unroll
  for (int i = 0; i < 4; ++i)
    #pragma unroll
    for (int j = 0; j < 4; ++j) acc[i][j] = z;

  int kTiles = K >> 5;
  for (int kt = 0; kt < kTiles; ++kt){
    int k0 = kt * 32;
    {                        // A tile 64 x 32: 256 uint4 chunks, one per thread
      int row = t >> 2, kc = t & 3;
      int gm = m0 + row; if (gm > M - 1) gm = M - 1;   // clamp (discarded in epilogue)
      *(uint4*)&As[row * 32 + kc * 8] = *(const uint4*)(A + (size_t)gm * K + k0 + kc * 8);
    }
    #pragma unroll
    for (int i = 0; i < 4; ++i){   // B tile 256 x 32: 1024 uint4 chunks
      int id = t + 256 * i;
      int row = id >> 2, kc = id & 3;
      *(uint4*)&Bs[row * 32 + kc * 8] = *(const uint4*)(Bp + (size_t)(n0 + row) * K + k0 + kc * 8);
    }
    __syncthreads();
    short8 af[4], bfr[4];
    #pragma unroll
    for (int mt = 0; mt < 4; ++mt)
      af[mt] = *(const short8*)&As[(mt * 16 + l16) * 32 + quad * 8];
    #pragma unroll
    for (int nt = 0; nt < 4; ++nt)
      bfr[nt] = *(const short8*)&Bs[(w * 64 + nt * 16 + l16) * 32 + quad * 8];
    #pragma unroll
    for (int nt = 0; nt < 4; ++nt)
      #pragma unroll
      for (int mt = 0; mt < 4; ++mt)
        acc[mt][nt] = __builtin_amdgcn_mfma_f32_16x16x32_bf16(af[mt], bfr[nt], acc[mt][nt], 0, 0, 0);
    __syncthreads();
  }
  // epilogue: +bias (+residual), store bf16 or fp32; out is channel-major [m][n]
  #pragma unroll
  for (int mt = 0; mt < 4; ++mt)
    #pragma unroll
    for (int nt = 0; nt < 4; ++nt){
      int n = n0 + w * 64 + nt * 16 + l16;
      #pragma unroll
      for (int r = 0; r < 4; ++r){
        int m = m0 + mt * 16 + quad * 4 + r;
        if (m < M){
          float v = acc[mt][nt][r] + bias[m];
          size_t idx = (size_t)blockIdx.z * M * N + (size_t)m * N + n;
          if (resid) v += resid[idx];
          if (ofp32) ((float*)outp)[idx] = v;
          else       ((unsigned short*)outp)[idx] = f2bf(v);
        }
      }
    }
}

// ---------------- depthwise 3x3 (SAME) + bias + fused q/k sum-of-squares ----------------
__global__ __launch_bounds__(256) void dw3_k(const unsigned short* __restrict__ in,
                                             const float* __restrict__ w, const float* __restrict__ bias,
                                             unsigned short* __restrict__ out, int C,
                                             float* __restrict__ qn, float* __restrict__ kn){
  __shared__ unsigned short tile[66 * 128];
  __shared__ float red[4];
  int zc = blockIdx.y;
  int b = zc / C, c = zc - b * C;
  int r0 = blockIdx.x * 64;
  const unsigned short* im = in + ((size_t)(b * C + c)) * HW;
  unsigned short* om = out + ((size_t)(b * C + c)) * HW;
  int t = threadIdx.x;
  #pragma unroll
  for (int i = 0; i < 5; ++i){
    int idx = t + 256 * i;
    if (idx < 1056){
      int lr = idx >> 4, lc = (idx & 15) * 8;
      int gr = r0 - 1 + lr;
      uint4 v = {0u, 0u, 0u, 0u};
      if ((unsigned)gr < 128u) v = *(const uint4*)(im + gr * 128 + lc);
      *(uint4*)&tile[lr * 128 + lc] = v;
    }
  }
  __syncthreads();
  const float* wc = w + c * 9;
  float W[9];
  #pragma unroll
  for (int i = 0; i < 9; ++i) W[i] = wc[i];
  float bs = bias[c];
  float ssq = 0.f;
  #pragma unroll
  for (int i = 0; i < 4; ++i){
    int seg = t + 256 * i;
    int orow = seg >> 4, sc = (seg & 15) * 8;
    float acc[8];
    #pragma unroll
    for (int j = 0; j < 8; ++j) acc[j] = bs;
    #pragma unroll
    for (int rr = 0; rr < 3; ++rr){
      const unsigned short* rp = &tile[(orow + rr) * 128 + sc];
      float v[10];
      v[0] = (sc > 0) ? bf2f(rp[-1]) : 0.f;
      uint4 m = *(const uint4*)rp;
      const unsigned short* mu = (const unsigned short*)&m;
      #pragma unroll
      for (int j = 0; j < 8; ++j) v[j + 1] = bf2f(mu[j]);
      v[9] = (sc < 120) ? bf2f(rp[8]) : 0.f;
      float wa = W[rr * 3], wb = W[rr * 3 + 1], wd = W[rr * 3 + 2];
      #pragma unroll
      for (int j = 0; j < 8; ++j) acc[j] += wa * v[j] + wb * v[j + 1] + wd * v[j + 2];
    }
    unsigned short ob[8];
    #pragma unroll
    for (int j = 0; j < 8; ++j){
      ob[j] = f2bf(acc[j]);
      float q = bf2f(ob[j]);
      ssq += q * q;
    }
    *(uint4*)(om + (r0 + orow) * 128 + sc) = *(uint4*)ob;
  }
  if (c < 384){   // block-uniform branch
    #pragma unroll
    for (int off = 32; off; off >>= 1) ssq += __shfl_down(ssq, off);
    if ((t & 63) == 0) red[t >> 6] = ssq;
    __syncthreads();
    if (t == 0){
      float s = red[0] + red[1] + red[2] + red[3];
      float* dst = (c < 192) ? (qn + b * 192 + c) : (kn + b * 192 + c - 192);
      atomicAdd(dst, s);
    }
  }
}

// ---------------- GDFN: g = dw(h[0:510]) * dw(h[510:1020]), channel-major out ----------------
__global__ __launch_bounds__(256) void dwgate_k(const unsigned short* __restrict__ h,
                                                const float* __restrict__ w, const float* __restrict__ bias,
                                                unsigned short* __restrict__ g){
  __shared__ unsigned short tile[2 * 66 * 128];
  int zc = blockIdx.y;
  int b = zc / 510, j = zc - b * 510;
  int r0 = blockIdx.x * 64;
  const unsigned short* im1 = h + ((size_t)(b * 1020 + j)) * HW;
  const unsigned short* im2 = h + ((size_t)(b * 1020 + 510 + j)) * HW;
  int t = threadIdx.x;
  #pragma unroll
  for (int i = 0; i < 9; ++i){
    int idx = t + 256 * i;
    if (idx < 2112){
      int img = (idx >= 1056) ? 1 : 0;
      int li = idx - img * 1056;
      int lr = li >> 4, lc = (li & 15) * 8;
      int gr = r0 - 1 + lr;
      uint4 v = {0u, 0u, 0u, 0u};
      const unsigned short* im = img ? im2 : im1;
      if ((unsigned)gr < 128u) v = *(const uint4*)(im + gr * 128 + lc);
      *(uint4*)&tile[img * 8448 + lr * 128 + lc] = v;
    }
  }
  __syncthreads();
  float W1[9], W2[9];
  #pragma unroll
  for (int i = 0; i < 9; ++i){ W1[i] = w[j * 9 + i]; W2[i] = w[(510 + j) * 9 + i]; }
  float b1 = bias[j], b2 = bias[510 + j];
  unsigned short* gm = g + ((size_t)(b * 510 + j)) * HW;
  #pragma unroll
  for (int i = 0; i < 4; ++i){
    int seg = t + 256 * i;
    int orow = seg >> 4, sc = (seg & 15) * 8;
    float a1[8], a2[8];
    #pragma unroll
    for (int q = 0; q < 8; ++q){ a1[q] = b1; a2[q] = b2; }
    #pragma unroll
    for (int rr = 0; rr < 3; ++rr){
      #pragma unroll
      for (int img = 0; img < 2; ++img){
        const unsigned short* rp = &tile[img * 8448 + (orow + rr) * 128 + sc];
        float v[10];
        v[0] = (sc > 0) ? bf2f(rp[-1]) : 0.f;
        uint4 m = *(const uint4*)rp;
        const unsigned short* mu = (const unsigned short*)&m;
        #pragma unroll
        for (int q = 0; q < 8; ++q) v[q + 1] = bf2f(mu[q]);
        v[9] = (sc < 120) ? bf2f(rp[8]) : 0.f;
        const float* ww = img ? W2 : W1;
        float* aa = img ? a2 : a1;
        float wa = ww[rr * 3], wb = ww[rr * 3 + 1], wd = ww[rr * 3 + 2];
        #pragma unroll
        for (int q = 0; q < 8; ++q) aa[q] += wa * v[q] + wb * v[q + 1] + wd * v[q + 2];
      }
    }
    unsigned short ob[8];
    #pragma unroll
    for (int q = 0; q < 8; ++q) ob[q] = f2bf(a1[q] * a2[q]);
    *(uint4*)(gm + (r0 + orow) * 128 + sc) = *(uint4*)ob;
  }
}

// ---------------- transpose [C][HW] -> [HW][Kout] bf16, zero-pad channels >= C ----------------
// grid (HW/64, Kout/64, B), block 256. 64ch x 64px tiles via LDS.
__global__ __launch_bounds__(256) void tr_k(const unsigned short* __restrict__ in,
                                            unsigned short* __restrict__ out, int C, int Kout){
  __shared__ unsigned short tile[64 * 72];
  int b = blockIdx.z;
  int p0 = blockIdx.x * 64, c0 = blockIdx.y * 64;
  int t = threadIdx.x;
  #pragma unroll
  for (int i = 0; i < 2; ++i){
    int id = t + 256 * i;               // 512 chunks: 64ch x 8
    int ch = id >> 3, pc = (id & 7) * 8;
    uint4 v = {0u, 0u, 0u, 0u};
    if (c0 + ch < C) v = *(const uint4*)(in + ((size_t)(b * C + c0 + ch)) * HW + p0 + pc);
    const unsigned short* u = (const unsigned short*)&v;
    #pragma unroll
    for (int j = 0; j < 8; ++j) tile[(pc + j) * 72 + ch] = u[j];
  }
  __syncthreads();
  #pragma unroll
  for (int i = 0; i < 2; ++i){
    int id = t + 256 * i;               // 512 chunks: 64px x 8
    int px = id >> 3, cc = (id & 7) * 8;
    *(uint4*)(out + ((size_t)b * HW + p0 + px) * Kout + c0 + cc) = *(const uint4*)&tile[px * 72 + cc];
  }
}

// ---------------- QK^T via MFMA, K-split partials. grid (32 ksplit, 32 bh), 1 wave ----------------
__global__ __launch_bounds__(64) void qk_k(const unsigned short* __restrict__ qkv_dw, float* __restrict__ part){
  int bh = blockIdx.y; int b = bh >> 3, h = bh & 7;
  int ks = blockIdx.x;
  int lane = threadIdx.x;
  int l16 = lane & 15, quad = lane >> 4;
  const unsigned short* qb = qkv_dw + ((size_t)b * 576 + h * 24) * HW;
  const unsigned short* kb = qkv_dw + ((size_t)b * 576 + 192 + h * 24) * HW;
  f32x4 z = {0.f, 0.f, 0.f, 0.f};
  f32x4 a00 = z, a01 = z, a10 = z, a11 = z;
  for (int st = 0; st < 16; ++st){
    int k0 = ks * 512 + st * 32 + quad * 8;
    short8 qa0 = *(const short8*)(qb + (size_t)l16 * HW + k0);
    short8 qa1 = *(const short8*)(qb + (size_t)(l16 + 16) * HW + k0);
    short8 kb0 = *(const short8*)(kb + (size_t)l16 * HW + k0);
    short8 kb1 = *(const short8*)(kb + (size_t)(l16 + 16) * HW + k0);
    a00 = __builtin_amdgcn_mfma_f32_16x16x32_bf16(qa0, kb0, a00, 0, 0, 0);
    a01 = __builtin_amdgcn_mfma_f32_16x16x32_bf16(qa0, kb1, a01, 0, 0, 0);
    a10 = __builtin_amdgcn_mfma_f32_16x16x32_bf16(qa1, kb0, a10, 0, 0, 0);
    a11 = __builtin_amdgcn_mfma_f32_16x16x32_bf16(qa1, kb1, a11, 0, 0, 0);
  }
  float* pp = part + ((size_t)bh * 32 + ks) * 576;
  #pragma unroll
  for (int r = 0; r < 4; ++r){
    int c0 = quad * 4 + r, c1 = 16 + quad * 4 + r;
    int d0 = l16, d1 = 16 + l16;
    if (c0 < 24 && d0 < 24) pp[c0 * 24 + d0] = a00[r];
    if (c0 < 24 && d1 < 24) pp[c0 * 24 + d1] = a01[r];
    if (c1 < 24 && d0 < 24) pp[c1 * 24 + d0] = a10[r];
    if (c1 < 24 && d1 < 24) pp[c1 * 24 + d1] = a11[r];
  }
}

// ---------------- reduce partials, scale by temp/(|q||k|), softmax over d ----------------
__global__ void softmax_k(const float* __restrict__ part, const float* __restrict__ qn,
                          const float* __restrict__ kn, const float* __restrict__ temp,
                          float* __restrict__ attn){
  int bh = blockIdx.x; int b = bh >> 3, h = bh & 7;
  int c = threadIdx.x;
  if (c >= 24) return;
  float tmp = temp[h];
  float qv = fmaxf(sqrtf(qn[b * 192 + h * 24 + c]), 1e-12f);
  float row[24];
  #pragma unroll
  for (int d = 0; d < 24; ++d){
    float s = 0.f;
    for (int sp = 0; sp < 32; ++sp) s += part[((size_t)bh * 32 + sp) * 576 + c * 24 + d];
    float kv = fmaxf(sqrtf(kn[b * 192 + h * 24 + d]), 1e-12f);
    row[d] = s * tmp / (qv * kv);
  }
  float mx = row[0];
  #pragma unroll
  for (int d = 1; d < 24; ++d) mx = fmaxf(mx, row[d]);
  float sum = 0.f;
  #pragma unroll
  for (int d = 0; d < 24; ++d){ row[d] = expf(row[d] - mx); sum += row[d]; }
  float inv = 1.f / sum;
  #pragma unroll
  for (int d = 0; d < 24; ++d) attn[(size_t)bh * 576 + c * 24 + d] = row[d] * inv;
}

// ---------------- out[p][c] = sum_d attn[c][d] * v[d][p]  (PIXEL-MAJOR out) ----------------
__global__ __launch_bounds__(256) void av_k(const float* __restrict__ attn,
                                            const unsigned short* __restrict__ qkv_dw,
                                            unsigned short* __restrict__ o){
  int bh = blockIdx.y; int b = bh >> 3, h = bh & 7;
  __shared__ float As[576];
  int t = threadIdx.x;
  for (int i = t; i < 576; i += 256) As[i] = attn[(size_t)bh * 576 + i];
  __syncthreads();
  int p = blockIdx.x * 256 + t;
  const unsigned short* vb = qkv_dw + ((size_t)b * 576 + 384 + h * 24) * HW + p;
  float acc[24];
  #pragma unroll
  for (int c = 0; c < 24; ++c) acc[c] = 0.f;
  #pragma unroll
  for (int d = 0; d < 24; ++d){
    float vv = bf2f(vb[(size_t)d * HW]);
    #pragma unroll
    for (int c = 0; c < 24; ++c) acc[c] += As[c * 24 + d] * vv;
  }
  unsigned short ob[24];
  #pragma unroll
  for (int c = 0; c < 24; ++c) ob[c] = f2bf(acc[c]);
  unsigned short* op = o + ((size_t)b * HW + p) * 192 + h * 24;
  #pragma unroll
  for (int i = 0; i < 3; ++i) *(uint4*)(op + i * 8) = *(const uint4*)(ob + i * 8);
}

extern "C" void kernel_launch(void* const* d_in, const int* in_sizes, int n_in,
                              void* d_out, int out_size, void* d_ws, size_t ws_size,
                              hipStream_t stream){
  (void)in_sizes; (void)n_in; (void)out_size; (void)ws_size;
  const float* x        = (const float*)d_in[0];
  const float* t_emb    = (const float*)d_in[1];
  const float* n1_w     = (const float*)d_in[2];
  const float* n1_b     = (const float*)d_in[3];
  const float* temp     = (const float*)d_in[4];
  const float* a_qkv_w  = (const float*)d_in[5];
  const float* a_qkv_b  = (const float*)d_in[6];
  const float* a_dw_w   = (const float*)d_in[7];
  const float* a_dw_b   = (const float*)d_in[8];
  const float* a_proj_w = (const float*)d_in[9];
  const float* a_proj_b = (const float*)d_in[10];
  const float* a_t_w    = (const float*)d_in[11];
  const float* a_t_b    = (const float*)d_in[12];
  const float* n2_w     = (const float*)d_in[13];
  const float* n2_b     = (const float*)d_in[14];
  const float* f_c1_w   = (const float*)d_in[15];
  const float* f_c1_b   = (const float*)d_in[16];
  const float* f_dw_w   = (const float*)d_in[17];
  const float* f_dw_b   = (const float*)d_in[18];
  const float* f_c2_w   = (const float*)d_in[19];
  const float* f_c2_b   = (const float*)d_in[20];
  const float* f_t_w    = (const float*)d_in[21];
  const float* f_t_b    = (const float*)d_in[22];
  float* out = (float*)d_out;
  char* ws = (char*)d_ws;

  // workspace layout (~229 MB, phase-overlapped)
  unsigned short* y_buf = (unsigned short*)(ws + 0);          // [b][p][192] 25.2MB
  unsigned short* qkv   = (unsigned short*)(ws + 25165824);   // [b][576][HW] 75.5MB (stage A)
  unsigned short* hbuf  = (unsigned short*)(ws + 25165824);   // [b][1020][HW] 133.7MB (stage B)
  unsigned short* gbufT = (unsigned short*)(ws + 25165824);   // [b][p][512] 67.1MB (after dwgate)
  unsigned short* qkvd  = (unsigned short*)(ws + 100663296);  // [b][576][HW] 75.5MB
  unsigned short* obuf  = (unsigned short*)(ws + 176160768);  // [b][p][192] 25.2MB
  unsigned short* gbuf  = (unsigned short*)(ws + 158859264);  // [b][510][HW] 66.8MB
  const size_t S = 225705984;
  float* mod_a = (float*)(ws + S);
  float* mod_f = (float*)(ws + S + 8192);
  float* qn    = (float*)(ws + S + 16384);
  float* kn    = (float*)(ws + S + 20480);
  float* part  = (float*)(ws + S + 24576);        // 2359296
  float* attn  = (float*)(ws + S + 2383872);      // 73728
  unsigned short* Wq  = (unsigned short*)(ws + S + 2457600);  // 576x192
  unsigned short* Wp  = (unsigned short*)(ws + S + 2678784);  // 192x192
  unsigned short* W1  = (unsigned short*)(ws + S + 2752512);  // 1020x192
  unsigned short* W2p = (unsigned short*)(ws + S + 3144192);  // 192x512 (padded)

  castw_k<<<dim3((110592 + 255) / 256), 256, 0, stream>>>(a_qkv_w, Wq, 110592);
  castw_k<<<dim3((36864 + 255) / 256), 256, 0, stream>>>(a_proj_w, Wp, 36864);
  castw_k<<<dim3((195840 + 255) / 256), 256, 0, stream>>>(f_c1_w, W1, 195840);
  castw_pad_k<<<dim3((98304 + 255) / 256), 256, 0, stream>>>(f_c2_w, W2p, 192, 510, 512);
  modk<<<dim3(3, 4, 2), 128, 0, stream>>>(t_emb, a_t_w, a_t_b, f_t_w, f_t_b, mod_a, mod_f);
  hipMemsetAsync(qn, 0, 2 * 768 * sizeof(float), stream);  // qn+kn contiguous

  // ---- MDTA branch ----
  lnmod_k<<<dim3(256, 4), 256, 0, stream>>>(x, n1_w, n1_b, mod_a, y_buf);
  gemm_tn<<<dim3(9, 64, 4), 256, 0, stream>>>(Wq, y_buf, a_qkv_b, nullptr, qkv, 576, 192, 0);
  dw3_k<<<dim3(2, 2304), 256, 0, stream>>>(qkv, a_dw_w, a_dw_b, qkvd, 576, qn, kn);
  qk_k<<<dim3(32, 32), 64, 0, stream>>>(qkvd, part);
  softmax_k<<<32, 64, 0, stream>>>(part, qn, kn, temp, attn);
  av_k<<<dim3(64, 32), 256, 0, stream>>>(attn, qkvd, obuf);
  gemm_tn<<<dim3(3, 64, 4), 256, 0, stream>>>(Wp, obuf, a_proj_b, x, out, 192, 192, 1); // out = x1

  // ---- GDFN branch ----
  lnmod_k<<<dim3(256, 4), 256, 0, stream>>>(out, n2_w, n2_b, mod_f, y_buf);
  gemm_tn<<<dim3(16, 64, 4), 256, 0, stream>>>(W1, y_buf, f_c1_b, nullptr, hbuf, 1020, 192, 0);
  dwgate_k<<<dim3(2, 2040), 256, 0, stream>>>(hbuf, f_dw_w, f_dw_b, gbuf);
  tr_k<<<dim3(256, 8, 4), 256, 0, stream>>>(gbuf, gbufT, 510, 512);
  gemm_tn<<<dim3(3, 64, 4), 256, 0, stream>>>(W2p, gbufT, f_c2_b, out, out, 192, 512, 1);
}